// Round 2
// baseline (1005.372 us; speedup 1.0000x reference)
//
#include <hip/hip_runtime.h>

#define ROWB 272            // bytes per row in slotted h layout (68 floats)
#define BUFA 0
#define BUFB 16384
#define PLOF 32768          // plane-1 region offset

#define LD4(o)   (*(const float4*)(sb + (o)))
#define LDF(o)   (*(const float*)(sb + (o)))
#define ST4(o,v) (*(float4*)(sb + (o)) = (v))
#define STF(o,v) (*(float*)(sb + (o)) = (v))

__global__ __launch_bounds__(448, 4)
void pde_fused2(const float* __restrict__ x,
                const float* __restrict__ conv_w,
                const float* __restrict__ conv_b,
                const float* __restrict__ bn_s,
                const float* __restrict__ bn_b,
                const float* __restrict__ bn_m,
                const float* __restrict__ bn_v,
                float* __restrict__ out,
                int C, int pairs)
{
    // regions: A0 [0,15232) | B0/xs0 [16384,..) | A1 [32768,..) | B1/xs1 [49152, 64384)
    __shared__ float smem[16096];
    char* sb = (char*)smem;

    const float DTc = 0.2f, EPSc = 1e-5f;
    const int bid = blockIdx.x;
    const int ch  = bid % C;
    const int tid = threadIdx.x;

    const size_t base0 = (size_t)bid * 3136;
    const size_t base1 = (size_t)(bid + pairs) * 3136;

    // ---- zero both padded 58x58 staging regions ----
    #pragma unroll
    for (int k = 0; k < 8; ++k) {
        int i = tid + k * 448;
        if (i < 3364) {
            STF(BUFB + i * 4, 0.0f);
            STF(BUFB + PLOF + i * 4, 0.0f);
        }
    }
    __syncthreads();

    // ---- coalesced global loads for both planes (14 loads in flight) ----
    float xv0[7], xv1[7];
    #pragma unroll
    for (int k = 0; k < 7; ++k) xv0[k] = x[base0 + tid + k * 448];
    #pragma unroll
    for (int k = 0; k < 7; ++k) xv1[k] = x[base1 + tid + k * 448];

    // ---- per-channel uniforms (shared by both planes: same channel) ----
    float wj[4][9], cbj[4];
    #pragma unroll
    for (int j = 0; j < 4; ++j) {
        #pragma unroll
        for (int t = 0; t < 9; ++t) wj[j][t] = conv_w[(j * C + ch) * 9 + t];
        cbj[j] = conv_b[j * C + ch];
    }
    float g[5], be[5];
    #pragma unroll
    for (int j = 0; j < 5; ++j) {
        float inv = bn_s[j * C + ch] * rsqrtf(bn_v[j * C + ch] + EPSc);
        g[j]  = inv;
        be[j] = bn_b[j * C + ch] - bn_m[j * C + ch] * inv;
    }

    #pragma unroll
    for (int k = 0; k < 7; ++k) {
        int idx = tid + k * 448;
        int rr = idx / 56, cc = idx - rr * 56;
        int o = ((rr + 1) * 58 + (cc + 1)) * 4;
        STF(BUFB + o, xv0[k]);
        STF(BUFB + PLOF + o, xv1[k]);
    }
    __syncthreads();

    // ---- this thread's 1x7 chunk ----
    const int r  = tid >> 3;
    const int cg = tid & 7;
    const int c0 = cg * 7;

    // ---- conv + BN + activations -> per-element coefficient planes ----
    float h[2][7], F[2][7], C0a[2][7], Cxp[2][7], Cxm[2][7], Cyp[2][7], Cym[2][7];
    #pragma unroll
    for (int p = 0; p < 2; ++p) {
        const int XB = BUFB + p * PLOF;
        float win[3][9];
        #pragma unroll
        for (int dr = 0; dr < 3; ++dr)
            #pragma unroll
            for (int dc = 0; dc < 9; ++dc)
                win[dr][dc] = LDF(XB + ((r + dr) * 58 + (c0 + dc)) * 4);

        #pragma unroll
        for (int i = 0; i < 7; ++i) {
            float a0 = cbj[0], a1 = cbj[1], a2 = cbj[2], a3 = cbj[3];
            #pragma unroll
            for (int dr = 0; dr < 3; ++dr)
                #pragma unroll
                for (int dc = 0; dc < 3; ++dc) {
                    float xw = win[dr][i + dc];
                    a0 = fmaf(xw, wj[0][dr * 3 + dc], a0);
                    a1 = fmaf(xw, wj[1][dr * 3 + dc], a1);
                    a2 = fmaf(xw, wj[2][dr * 3 + dc], a2);
                    a3 = fmaf(xw, wj[3][dr * 3 + dc], a3);
                }
            float uu  = fmaxf(fmaf(a0, g[0], be[0]), 0.0f);
            float vv  = fmaxf(fmaf(a1, g[1], be[1]), 0.0f);
            float z2  = fmaf(a2, g[2], be[2]);
            float z3  = fmaf(a3, g[3], be[3]);
            float Dxv = 1.0f / (1.0f + __expf(-z2));
            float Dyv = 1.0f / (1.0f + __expf(-z3));
            float A = DTc * Dxv, Bv = DTc * Dyv;
            float U = 0.5f * DTc * uu, V = 0.5f * DTc * vv;
            float hv = win[1][i + 1];
            h[p][i]   = hv;
            F[p][i]   = DTc * hv;
            C0a[p][i] = 1.0f - 2.0f * A - 2.0f * Bv;
            Cxp[p][i] = A + U;   Cxm[p][i] = A - U;
            Cyp[p][i] = Bv + V;  Cym[p][i] = Bv - V;
        }
    }

    // ---- slotted-layout addresses (shared by both planes/buffers via imm offsets) ----
    const int rm = (r == 0)  ? 55 : r - 1;
    const int rp = (r == 55) ? 0  : r + 1;
    const int a_me = r  * ROWB + cg * 32;
    const int a_up = rm * ROWB + cg * 32;
    const int a_dn = rp * ROWB + cg * 32;
    const int a_l  = r  * ROWB + ((cg + 7) & 7) * 32 + 24;  // left nbr: chunk-1, elem 6
    const int a_r  = r  * ROWB + ((cg + 1) & 7) * 32;       // right nbr: chunk+1, elem 0

    // initial h into A buffers
    #pragma unroll
    for (int p = 0; p < 2; ++p) {
        ST4(BUFA + p * PLOF + a_me,      make_float4(h[p][0], h[p][1], h[p][2], h[p][3]));
        ST4(BUFA + p * PLOF + a_me + 16, make_float4(h[p][4], h[p][5], h[p][6], h[p][6]));
    }
    __syncthreads();

#define STEP(CUR, NXT) do {                                                   \
    _Pragma("unroll")                                                         \
    for (int p = 0; p < 2; ++p) {                                             \
        const int RB = (CUR) + p * PLOF;                                      \
        const int WB = (NXT) + p * PLOF;                                      \
        float4 ua = LD4(RB + a_up), ub = LD4(RB + a_up + 16);                 \
        float4 da = LD4(RB + a_dn), db = LD4(RB + a_dn + 16);                 \
        float lf = LDF(RB + a_l);                                             \
        float rg = LDF(RB + a_r);                                             \
        float u7[7] = {ua.x, ua.y, ua.z, ua.w, ub.x, ub.y, ub.z};             \
        float d7[7] = {da.x, da.y, da.z, da.w, db.x, db.y, db.z};             \
        float nh[7];                                                          \
        _Pragma("unroll")                                                     \
        for (int i = 0; i < 7; ++i) {                                         \
            float hl = (i == 0) ? lf : h[p][i - 1];                           \
            float hr = (i == 6) ? rg : h[p][i + 1];                           \
            float t = fmaf(C0a[p][i], h[p][i], F[p][i]);                      \
            t = fmaf(Cxm[p][i], u7[i], t);                                    \
            t = fmaf(Cxp[p][i], d7[i], t);                                    \
            t = fmaf(Cym[p][i], hl, t);                                       \
            t = fmaf(Cyp[p][i], hr, t);                                       \
            nh[i] = t;                                                        \
        }                                                                     \
        ST4(WB + a_me,      make_float4(nh[0], nh[1], nh[2], nh[3]));         \
        ST4(WB + a_me + 16, make_float4(nh[4], nh[5], nh[6], nh[6]));         \
        _Pragma("unroll")                                                     \
        for (int i = 0; i < 7; ++i) h[p][i] = nh[i];                          \
    }                                                                         \
    __syncthreads();                                                          \
} while (0)

    for (int s = 0; s < 5; ++s) {
        STEP(BUFA, BUFB);
        STEP(BUFB, BUFA);
    }
#undef STEP

    // ---- final bn4 + relu, store straight from registers ----
    #pragma unroll
    for (int p = 0; p < 2; ++p) {
        size_t ob = (p == 0 ? base0 : base1) + (size_t)r * 56 + c0;
        #pragma unroll
        for (int i = 0; i < 7; ++i) {
            float y = fmaf(h[p][i], g[4], be[4]);
            out[ob + i] = fmaxf(y, 0.0f);
        }
    }
}

extern "C" void kernel_launch(void* const* d_in, const int* in_sizes, int n_in,
                              void* d_out, int out_size, void* d_ws, size_t ws_size,
                              hipStream_t stream) {
    const float* x  = (const float*)d_in[0];
    const float* cw = (const float*)d_in[1];
    const float* cb = (const float*)d_in[2];
    const float* bs = (const float*)d_in[3];
    const float* bb = (const float*)d_in[4];
    const float* bm = (const float*)d_in[5];
    const float* bv = (const float*)d_in[6];
    float* out = (float*)d_out;

    int C = in_sizes[2] / 4;            // conv_b is [4, C]
    int planes = in_sizes[0] / 3136;    // B*C planes of 56*56
    int pairs = planes / 2;             // plane p pairs with p + pairs (same channel: pairs % C == 0)

    pde_fused2<<<pairs, 448, 0, stream>>>(x, cw, cb, bs, bb, bm, bv, out, C, pairs);
}

// Round 3
// 272.805 us; speedup vs baseline: 3.6853x; 3.6853x over previous
//
#include <hip/hip_runtime.h>

#define K_STEPS 10

__global__ __launch_bounds__(896)
void pde_fused3(const float* __restrict__ x,
                const float* __restrict__ conv_w,
                const float* __restrict__ conv_b,
                const float* __restrict__ bn_s,
                const float* __restrict__ bn_b,
                const float* __restrict__ bn_m,
                const float* __restrict__ bn_v,
                float* __restrict__ out,
                int C)
{
    const float DTc = 0.2f, EPSc = 1e-5f;
    // two independent 26KB plane regions; waves 0-6 -> p=0, waves 7-13 -> p=1
    __shared__ float smem[2 * 6500];
    const int p  = (threadIdx.x >= 448) ? 1 : 0;
    const int t  = threadIdx.x - p * 448;
    const int plane = blockIdx.x * 2 + p;
    const int ch = plane % C;
    const size_t base = (size_t)plane * 3136;

    float* xs  = smem + p * 6500;   // [58][58] zero-padded x tile
    float* hbA = xs + 3364;         // [56][56]
    float* hbB = xs;                // [56][56], aliases xs (dead after setup)

    // ---- stage x into padded LDS (coalesced global loads) ----
    for (int i = t; i < 3364; i += 448) xs[i] = 0.0f;
    __syncthreads();
    float xv[7];
    #pragma unroll
    for (int k = 0; k < 7; ++k) xv[k] = x[base + t + k * 448];
    #pragma unroll
    for (int k = 0; k < 7; ++k) {
        int idx = t + k * 448;
        int rr = idx / 56, cc = idx - rr * 56;
        xs[(rr + 1) * 58 + (cc + 1)] = xv[k];
    }
    __syncthreads();

    // ---- per-channel uniforms (wave-uniform addresses -> scalar loads) ----
    float wj[4][9], cbj[4];
    #pragma unroll
    for (int j = 0; j < 4; ++j) {
        #pragma unroll
        for (int tt = 0; tt < 9; ++tt) wj[j][tt] = conv_w[(j * C + ch) * 9 + tt];
        cbj[j] = conv_b[j * C + ch];
    }
    float g[5], be[5];
    #pragma unroll
    for (int j = 0; j < 5; ++j) {
        float inv = bn_s[j * C + ch] * rsqrtf(bn_v[j * C + ch] + EPSc);
        g[j]  = inv;
        be[j] = bn_b[j * C + ch] - bn_m[j * C + ch] * inv;
    }

    // ---- this thread's 1x7 chunk: row r, cols c0..c0+6 ----
    const int r  = t >> 3;
    const int c0 = (t & 7) * 7;

    // conv window: rows r..r+2, cols c0..c0+8 (padded coords)
    float win[3][9];
    #pragma unroll
    for (int dr = 0; dr < 3; ++dr)
        #pragma unroll
        for (int dc = 0; dc < 9; ++dc)
            win[dr][dc] = xs[(r + dr) * 58 + c0 + dc];

    // coefficient planes: h' = C0*h + Cxm*up + Cxp*dn + Cym*left + Cyp*right + F
    float h[7], F[7], C0[7], Cxp[7], Cxm[7], Cyp[7], Cym[7];
    #pragma unroll
    for (int i = 0; i < 7; ++i) {
        float a0 = cbj[0], a1 = cbj[1], a2 = cbj[2], a3 = cbj[3];
        #pragma unroll
        for (int dr = 0; dr < 3; ++dr)
            #pragma unroll
            for (int dc = 0; dc < 3; ++dc) {
                float xw = win[dr][i + dc];
                a0 = fmaf(xw, wj[0][dr * 3 + dc], a0);
                a1 = fmaf(xw, wj[1][dr * 3 + dc], a1);
                a2 = fmaf(xw, wj[2][dr * 3 + dc], a2);
                a3 = fmaf(xw, wj[3][dr * 3 + dc], a3);
            }
        float uu  = fmaxf(fmaf(a0, g[0], be[0]), 0.0f);   // relu(bn0)
        float vv  = fmaxf(fmaf(a1, g[1], be[1]), 0.0f);   // relu(bn1)
        float z2  = fmaf(a2, g[2], be[2]);
        float z3  = fmaf(a3, g[3], be[3]);
        float Dxv = 1.0f / (1.0f + __expf(-z2));          // sigmoid(bn2), CDX=1
        float Dyv = 1.0f / (1.0f + __expf(-z3));          // sigmoid(bn3), CDY=1
        float A = DTc * Dxv, Bv = DTc * Dyv;
        float U = 0.5f * DTc * uu, V = 0.5f * DTc * vv;
        float hv = win[1][i + 1];                         // x at (r, c0+i)
        h[i]   = hv;
        F[i]   = DTc * hv;
        C0[i]  = 1.0f - 2.0f * A - 2.0f * Bv;
        Cxp[i] = A + U;   Cxm[i] = A - U;                 // row+1 / row-1 (axis 2)
        Cyp[i] = Bv + V;  Cym[i] = Bv - V;                // col+1 / col-1 (axis 3)
    }

    // initial h into buffer A
    #pragma unroll
    for (int i = 0; i < 7; ++i) hbA[r * 56 + c0 + i] = h[i];
    __syncthreads();

    // periodic-wrap neighbor indices (jnp.roll semantics)
    const int rm = (r == 0)  ? 55 : r - 1;
    const int rp = (r == 55) ? 0  : r + 1;
    const int lidx = r * 56 + ((c0 == 0)  ? 55 : c0 - 1);
    const int ridx = r * 56 + ((c0 == 49) ? 0  : c0 + 7);

    float* cur = hbA;
    float* nxt = hbB;
    #pragma unroll
    for (int s = 0; s < K_STEPS; ++s) {
        float up[7], dn[7];
        #pragma unroll
        for (int i = 0; i < 7; ++i) up[i] = cur[rm * 56 + c0 + i];
        #pragma unroll
        for (int i = 0; i < 7; ++i) dn[i] = cur[rp * 56 + c0 + i];
        float lf = cur[lidx];
        float rg = cur[ridx];
        float nh[7];
        #pragma unroll
        for (int i = 0; i < 7; ++i) {
            float hl = (i == 0) ? lf : h[i - 1];
            float hr = (i == 6) ? rg : h[i + 1];
            float tv = fmaf(C0[i], h[i], F[i]);
            tv = fmaf(Cxm[i], up[i], tv);
            tv = fmaf(Cxp[i], dn[i], tv);
            tv = fmaf(Cym[i], hl, tv);
            tv = fmaf(Cyp[i], hr, tv);
            nh[i] = tv;
        }
        #pragma unroll
        for (int i = 0; i < 7; ++i) nxt[r * 56 + c0 + i] = nh[i];
        #pragma unroll
        for (int i = 0; i < 7; ++i) h[i] = nh[i];
        __syncthreads();
        float* t2 = cur; cur = nxt; nxt = t2;
    }

    // ---- final bn4 + relu, coalesced store ----
    #pragma unroll
    for (int k = 0; k < 7; ++k) {
        int idx = t + k * 448;
        float y = fmaf(cur[idx], g[4], be[4]);
        out[base + idx] = fmaxf(y, 0.0f);
    }
}

extern "C" void kernel_launch(void* const* d_in, const int* in_sizes, int n_in,
                              void* d_out, int out_size, void* d_ws, size_t ws_size,
                              hipStream_t stream) {
    const float* x  = (const float*)d_in[0];
    const float* cw = (const float*)d_in[1];
    const float* cb = (const float*)d_in[2];
    const float* bs = (const float*)d_in[3];
    const float* bb = (const float*)d_in[4];
    const float* bm = (const float*)d_in[5];
    const float* bv = (const float*)d_in[6];
    float* out = (float*)d_out;

    int C = in_sizes[2] / 4;            // conv_b is [4, C]
    int planes = in_sizes[0] / 3136;    // B*C planes of 56*56

    pde_fused3<<<planes / 2, 896, 0, stream>>>(x, cw, cb, bs, bb, bm, bv, out, C);
}

// Round 4
// 268.175 us; speedup vs baseline: 3.7489x; 1.0173x over previous
//
#include <hip/hip_runtime.h>

#define K_STEPS 10

__global__ __launch_bounds__(448, 2)
void pde_fused4(const float* __restrict__ x,
                const float* __restrict__ conv_w,
                const float* __restrict__ conv_b,
                const float* __restrict__ bn_s,
                const float* __restrict__ bn_b,
                const float* __restrict__ bn_m,
                const float* __restrict__ bn_v,
                float* __restrict__ out,
                int C, int pairs)
{
    const float DTc = 0.2f, EPSc = 1e-5f;
    __shared__ float smem[2 * 6500];
    const int tid = threadIdx.x;
    const int bid = blockIdx.x;
    const int ch  = bid % C;                    // (bid+pairs) has same channel: pairs % C == 0
    const size_t base0 = (size_t)bid * 3136;
    const size_t base1 = (size_t)(bid + pairs) * 3136;

    float* xs0 = smem;                 // [58][58] padded x tile, plane 0
    float* xs1 = smem + 6500;          // plane 1
    float* hA0 = smem + 3364;          // [56][56]
    float* hA1 = smem + 6500 + 3364;
    float* hB0 = xs0;                  // aliases xs (dead after setup)
    float* hB1 = xs1;

    // ---- zero both padded staging tiles ----
    for (int i = tid; i < 3364; i += 448) { xs0[i] = 0.0f; xs1[i] = 0.0f; }
    __syncthreads();

    // ---- coalesced global loads, both planes issued back-to-back ----
    float xv0[7], xv1[7];
    #pragma unroll
    for (int k = 0; k < 7; ++k) xv0[k] = x[base0 + tid + k * 448];
    #pragma unroll
    for (int k = 0; k < 7; ++k) xv1[k] = x[base1 + tid + k * 448];

    // ---- per-channel uniforms (block-uniform -> scalar loads), shared by both planes ----
    float wj[4][9], cbj[4];
    #pragma unroll
    for (int j = 0; j < 4; ++j) {
        #pragma unroll
        for (int tt = 0; tt < 9; ++tt) wj[j][tt] = conv_w[(j * C + ch) * 9 + tt];
        cbj[j] = conv_b[j * C + ch];
    }
    float g[5], be[5];
    #pragma unroll
    for (int j = 0; j < 5; ++j) {
        float inv = bn_s[j * C + ch] * rsqrtf(bn_v[j * C + ch] + EPSc);
        g[j]  = inv;
        be[j] = bn_b[j * C + ch] - bn_m[j * C + ch] * inv;
    }

    #pragma unroll
    for (int k = 0; k < 7; ++k) {
        int idx = tid + k * 448;
        int rr = idx / 56, cc = idx - rr * 56;
        int o = (rr + 1) * 58 + (cc + 1);
        xs0[o] = xv0[k];
        xs1[o] = xv1[k];
    }
    __syncthreads();

    // ---- this thread's 1x7 chunk ----
    const int r  = tid >> 3;
    const int c0 = (tid & 7) * 7;

    // ---- conv + BN + activation -> coefficient planes, both planes ----
    float h0[7], F0[7], A0[7], Xp0[7], Xm0[7], Yp0[7], Ym0[7];
    float h1[7], F1[7], A1[7], Xp1[7], Xm1[7], Yp1[7], Ym1[7];

#define SETUP(XS, H, F, A, XP, XM, YP, YM) do {                               \
    float win[3][9];                                                          \
    _Pragma("unroll")                                                         \
    for (int dr = 0; dr < 3; ++dr)                                            \
        _Pragma("unroll")                                                     \
        for (int dc = 0; dc < 9; ++dc)                                        \
            win[dr][dc] = (XS)[(r + dr) * 58 + c0 + dc];                      \
    _Pragma("unroll")                                                         \
    for (int i = 0; i < 7; ++i) {                                             \
        float a0 = cbj[0], a1 = cbj[1], a2 = cbj[2], a3 = cbj[3];             \
        _Pragma("unroll")                                                     \
        for (int dr = 0; dr < 3; ++dr)                                        \
            _Pragma("unroll")                                                 \
            for (int dc = 0; dc < 3; ++dc) {                                  \
                float xw = win[dr][i + dc];                                   \
                a0 = fmaf(xw, wj[0][dr * 3 + dc], a0);                        \
                a1 = fmaf(xw, wj[1][dr * 3 + dc], a1);                        \
                a2 = fmaf(xw, wj[2][dr * 3 + dc], a2);                        \
                a3 = fmaf(xw, wj[3][dr * 3 + dc], a3);                        \
            }                                                                 \
        float uu  = fmaxf(fmaf(a0, g[0], be[0]), 0.0f);                       \
        float vv  = fmaxf(fmaf(a1, g[1], be[1]), 0.0f);                       \
        float z2  = fmaf(a2, g[2], be[2]);                                    \
        float z3  = fmaf(a3, g[3], be[3]);                                    \
        float Dxv = 1.0f / (1.0f + __expf(-z2));                              \
        float Dyv = 1.0f / (1.0f + __expf(-z3));                              \
        float Aa = DTc * Dxv, Bb = DTc * Dyv;                                 \
        float U = 0.5f * DTc * uu, V = 0.5f * DTc * vv;                       \
        float hv = win[1][i + 1];                                             \
        (H)[i]  = hv;                                                         \
        (F)[i]  = DTc * hv;                                                   \
        (A)[i]  = 1.0f - 2.0f * Aa - 2.0f * Bb;                               \
        (XP)[i] = Aa + U;  (XM)[i] = Aa - U;                                  \
        (YP)[i] = Bb + V;  (YM)[i] = Bb - V;                                  \
    }                                                                         \
} while (0)

    SETUP(xs0, h0, F0, A0, Xp0, Xm0, Yp0, Ym0);
    SETUP(xs1, h1, F1, A1, Xp1, Xm1, Yp1, Ym1);
#undef SETUP

    // initial h into A buffers
    const int o_me = r * 56 + c0;
    #pragma unroll
    for (int i = 0; i < 7; ++i) { hA0[o_me + i] = h0[i]; hA1[o_me + i] = h1[i]; }
    __syncthreads();

    // periodic-wrap neighbor offsets (jnp.roll semantics)
    const int rm = (r == 0)  ? 55 : r - 1;
    const int rp = (r == 55) ? 0  : r + 1;
    const int o_up = rm * 56 + c0;
    const int o_dn = rp * 56 + c0;
    const int o_l  = r * 56 + ((c0 == 0)  ? 55 : c0 - 1);
    const int o_r  = r * 56 + ((c0 == 49) ? 0  : c0 + 7);

    float *cur0 = hA0, *nxt0 = hB0, *cur1 = hA1, *nxt1 = hB1;
    #pragma unroll
    for (int s = 0; s < K_STEPS; ++s) {
        // --- issue ALL LDS reads for both planes first (p1 drain hides under p0 compute) ---
        float u0[7], d0[7], u1[7], d1[7];
        #pragma unroll
        for (int i = 0; i < 7; ++i) u0[i] = cur0[o_up + i];
        #pragma unroll
        for (int i = 0; i < 7; ++i) d0[i] = cur0[o_dn + i];
        float lf0 = cur0[o_l], rg0 = cur0[o_r];
        #pragma unroll
        for (int i = 0; i < 7; ++i) u1[i] = cur1[o_up + i];
        #pragma unroll
        for (int i = 0; i < 7; ++i) d1[i] = cur1[o_dn + i];
        float lf1 = cur1[o_l], rg1 = cur1[o_r];

        // --- plane 0 compute + write ---
        float nh0[7];
        #pragma unroll
        for (int i = 0; i < 7; ++i) {
            float hl = (i == 0) ? lf0 : h0[i - 1];
            float hr = (i == 6) ? rg0 : h0[i + 1];
            float tv = fmaf(A0[i], h0[i], F0[i]);
            tv = fmaf(Xm0[i], u0[i], tv);
            tv = fmaf(Xp0[i], d0[i], tv);
            tv = fmaf(Ym0[i], hl, tv);
            tv = fmaf(Yp0[i], hr, tv);
            nh0[i] = tv;
        }
        #pragma unroll
        for (int i = 0; i < 7; ++i) nxt0[o_me + i] = nh0[i];

        // --- plane 1 compute + write ---
        float nh1[7];
        #pragma unroll
        for (int i = 0; i < 7; ++i) {
            float hl = (i == 0) ? lf1 : h1[i - 1];
            float hr = (i == 6) ? rg1 : h1[i + 1];
            float tv = fmaf(A1[i], h1[i], F1[i]);
            tv = fmaf(Xm1[i], u1[i], tv);
            tv = fmaf(Xp1[i], d1[i], tv);
            tv = fmaf(Ym1[i], hl, tv);
            tv = fmaf(Yp1[i], hr, tv);
            nh1[i] = tv;
        }
        #pragma unroll
        for (int i = 0; i < 7; ++i) nxt1[o_me + i] = nh1[i];

        #pragma unroll
        for (int i = 0; i < 7; ++i) { h0[i] = nh0[i]; h1[i] = nh1[i]; }
        __syncthreads();
        float* t2;
        t2 = cur0; cur0 = nxt0; nxt0 = t2;
        t2 = cur1; cur1 = nxt1; nxt1 = t2;
    }

    // ---- final bn4 + relu, coalesced stores (re-read through LDS) ----
    #pragma unroll
    for (int k = 0; k < 7; ++k) {
        int idx = tid + k * 448;
        float y0 = fmaf(cur0[idx], g[4], be[4]);
        float y1 = fmaf(cur1[idx], g[4], be[4]);
        out[base0 + idx] = fmaxf(y0, 0.0f);
        out[base1 + idx] = fmaxf(y1, 0.0f);
    }
}

extern "C" void kernel_launch(void* const* d_in, const int* in_sizes, int n_in,
                              void* d_out, int out_size, void* d_ws, size_t ws_size,
                              hipStream_t stream) {
    const float* x  = (const float*)d_in[0];
    const float* cw = (const float*)d_in[1];
    const float* cb = (const float*)d_in[2];
    const float* bs = (const float*)d_in[3];
    const float* bb = (const float*)d_in[4];
    const float* bm = (const float*)d_in[5];
    const float* bv = (const float*)d_in[6];
    float* out = (float*)d_out;

    int C = in_sizes[2] / 4;            // conv_b is [4, C]
    int planes = in_sizes[0] / 3136;    // B*C planes of 56*56
    int pairs = planes / 2;             // plane p pairs with p+pairs (same channel: pairs % C == 0)

    pde_fused4<<<pairs, 448, 0, stream>>>(x, cw, cb, bs, bb, bm, bv, out, C, pairs);
}

// Round 5
// 166.033 us; speedup vs baseline: 6.0553x; 1.6152x over previous
//
#include <hip/hip_runtime.h>

#define K_STEPS 10

__device__ __forceinline__ float2 fma2(float2 a, float2 b, float2 c) {
    return make_float2(fmaf(a.x, b.x, c.x), fmaf(a.y, b.y, c.y));
}
__device__ __forceinline__ float2 fma2s(float2 a, float s, float2 c) {
    return make_float2(fmaf(a.x, s, c.x), fmaf(a.y, s, c.y));
}

__global__ __launch_bounds__(448)
void pde_fused5(const float* __restrict__ x,
                const float* __restrict__ conv_w,
                const float* __restrict__ conv_b,
                const float* __restrict__ bn_s,
                const float* __restrict__ bn_b,
                const float* __restrict__ bn_m,
                const float* __restrict__ bn_v,
                float* __restrict__ out,
                int C, int pairs)
{
    const float DTc = 0.2f, EPSc = 1e-5f;
    // float2 = {plane bid, plane bid+pairs}; same channel since pairs % C == 0
    __shared__ float2 smem[6500];
    const int tid = threadIdx.x;
    const int bid = blockIdx.x;
    const int ch  = bid % C;
    const size_t base0 = (size_t)bid * 3136;
    const size_t base1 = (size_t)(bid + pairs) * 3136;

    float2* xs = smem;          // [58][58] zero-padded x tile (both planes)
    float2* hA = smem + 3364;   // [56][56]
    float2* hB = smem;          // aliases xs (dead after setup)

    // ---- zero padded staging tile ----
    for (int i = tid; i < 3364; i += 448) xs[i] = make_float2(0.0f, 0.0f);
    __syncthreads();

    // ---- coalesced global loads, both planes ----
    float xv0[7], xv1[7];
    #pragma unroll
    for (int k = 0; k < 7; ++k) xv0[k] = x[base0 + tid + k * 448];
    #pragma unroll
    for (int k = 0; k < 7; ++k) xv1[k] = x[base1 + tid + k * 448];

    // ---- per-channel uniforms (block-uniform -> scalar loads) ----
    float wj[4][9], cbj[4];
    #pragma unroll
    for (int j = 0; j < 4; ++j) {
        #pragma unroll
        for (int tt = 0; tt < 9; ++tt) wj[j][tt] = conv_w[(j * C + ch) * 9 + tt];
        cbj[j] = conv_b[j * C + ch];
    }
    float g[5], be[5];
    #pragma unroll
    for (int j = 0; j < 5; ++j) {
        float inv = bn_s[j * C + ch] * rsqrtf(bn_v[j * C + ch] + EPSc);
        g[j]  = inv;
        be[j] = bn_b[j * C + ch] - bn_m[j * C + ch] * inv;
    }

    #pragma unroll
    for (int k = 0; k < 7; ++k) {
        int idx = tid + k * 448;
        int rr = idx / 56, cc = idx - rr * 56;
        xs[(rr + 1) * 58 + (cc + 1)] = make_float2(xv0[k], xv1[k]);
    }
    __syncthreads();

    // ---- this thread's 1x7 chunk: row r, cols c0..c0+6 (both planes) ----
    const int r  = tid >> 3;
    const int c0 = (tid & 7) * 7;

    // conv window, both planes per float2
    float2 win[3][9];
    #pragma unroll
    for (int dr = 0; dr < 3; ++dr)
        #pragma unroll
        for (int dc = 0; dc < 9; ++dc)
            win[dr][dc] = xs[(r + dr) * 58 + c0 + dc];

    // coefficient planes (float2 per element): h' = A*h + Xm*up + Xp*dn + Ym*l + Yp*r + F
    float2 h[7], F[7], A[7], Xp[7], Xm[7], Yp[7], Ym[7];
    #pragma unroll
    for (int i = 0; i < 7; ++i) {
        float2 a0 = make_float2(cbj[0], cbj[0]);
        float2 a1 = make_float2(cbj[1], cbj[1]);
        float2 a2 = make_float2(cbj[2], cbj[2]);
        float2 a3 = make_float2(cbj[3], cbj[3]);
        #pragma unroll
        for (int dr = 0; dr < 3; ++dr)
            #pragma unroll
            for (int dc = 0; dc < 3; ++dc) {
                float2 xw = win[dr][i + dc];
                a0 = fma2s(xw, wj[0][dr * 3 + dc], a0);
                a1 = fma2s(xw, wj[1][dr * 3 + dc], a1);
                a2 = fma2s(xw, wj[2][dr * 3 + dc], a2);
                a3 = fma2s(xw, wj[3][dr * 3 + dc], a3);
            }
        float uux = fmaxf(fmaf(a0.x, g[0], be[0]), 0.0f);
        float uuy = fmaxf(fmaf(a0.y, g[0], be[0]), 0.0f);
        float vvx = fmaxf(fmaf(a1.x, g[1], be[1]), 0.0f);
        float vvy = fmaxf(fmaf(a1.y, g[1], be[1]), 0.0f);
        float z2x = fmaf(a2.x, g[2], be[2]), z2y = fmaf(a2.y, g[2], be[2]);
        float z3x = fmaf(a3.x, g[3], be[3]), z3y = fmaf(a3.y, g[3], be[3]);
        float Dxx = 1.0f / (1.0f + __expf(-z2x));
        float Dxy = 1.0f / (1.0f + __expf(-z2y));
        float Dyx = 1.0f / (1.0f + __expf(-z3x));
        float Dyy = 1.0f / (1.0f + __expf(-z3y));
        float2 Aa = make_float2(DTc * Dxx, DTc * Dxy);
        float2 Bb = make_float2(DTc * Dyx, DTc * Dyy);
        float2 U  = make_float2(0.5f * DTc * uux, 0.5f * DTc * uuy);
        float2 V  = make_float2(0.5f * DTc * vvx, 0.5f * DTc * vvy);
        float2 hv = win[1][i + 1];
        h[i]  = hv;
        F[i]  = make_float2(DTc * hv.x, DTc * hv.y);
        A[i]  = make_float2(1.0f - 2.0f * Aa.x - 2.0f * Bb.x,
                            1.0f - 2.0f * Aa.y - 2.0f * Bb.y);
        Xp[i] = make_float2(Aa.x + U.x, Aa.y + U.y);
        Xm[i] = make_float2(Aa.x - U.x, Aa.y - U.y);
        Yp[i] = make_float2(Bb.x + V.x, Bb.y + V.y);
        Ym[i] = make_float2(Bb.x - V.x, Bb.y - V.y);
    }

    // initial h into buffer A
    const int o_me = r * 56 + c0;
    #pragma unroll
    for (int i = 0; i < 7; ++i) hA[o_me + i] = h[i];
    __syncthreads();

    // periodic-wrap neighbor offsets (jnp.roll semantics)
    const int rm = (r == 0)  ? 55 : r - 1;
    const int rp = (r == 55) ? 0  : r + 1;
    const int o_up = rm * 56 + c0;
    const int o_dn = rp * 56 + c0;
    const int o_l  = r * 56 + ((c0 == 0)  ? 55 : c0 - 1);
    const int o_r  = r * 56 + ((c0 == 49) ? 0  : c0 + 7);

    float2 *cur = hA, *nxt = hB;
    #pragma unroll
    for (int s = 0; s < K_STEPS; ++s) {
        float2 up[7], dn[7];
        #pragma unroll
        for (int i = 0; i < 7; ++i) up[i] = cur[o_up + i];
        #pragma unroll
        for (int i = 0; i < 7; ++i) dn[i] = cur[o_dn + i];
        float2 lf = cur[o_l];
        float2 rg = cur[o_r];
        float2 nh[7];
        #pragma unroll
        for (int i = 0; i < 7; ++i) {
            float2 hl = (i == 0) ? lf : h[i - 1];
            float2 hr = (i == 6) ? rg : h[i + 1];
            float2 tv = fma2(A[i], h[i], F[i]);
            tv = fma2(Xm[i], up[i], tv);
            tv = fma2(Xp[i], dn[i], tv);
            tv = fma2(Ym[i], hl, tv);
            tv = fma2(Yp[i], hr, tv);
            nh[i] = tv;
        }
        #pragma unroll
        for (int i = 0; i < 7; ++i) nxt[o_me + i] = nh[i];
        #pragma unroll
        for (int i = 0; i < 7; ++i) h[i] = nh[i];
        __syncthreads();
        float2* t2 = cur; cur = nxt; nxt = t2;
    }

    // ---- final bn4 + relu, coalesced stores via LDS re-read ----
    #pragma unroll
    for (int k = 0; k < 7; ++k) {
        int idx = tid + k * 448;
        float2 v = cur[idx];
        out[base0 + idx] = fmaxf(fmaf(v.x, g[4], be[4]), 0.0f);
        out[base1 + idx] = fmaxf(fmaf(v.y, g[4], be[4]), 0.0f);
    }
}

extern "C" void kernel_launch(void* const* d_in, const int* in_sizes, int n_in,
                              void* d_out, int out_size, void* d_ws, size_t ws_size,
                              hipStream_t stream) {
    const float* x  = (const float*)d_in[0];
    const float* cw = (const float*)d_in[1];
    const float* cb = (const float*)d_in[2];
    const float* bs = (const float*)d_in[3];
    const float* bb = (const float*)d_in[4];
    const float* bm = (const float*)d_in[5];
    const float* bv = (const float*)d_in[6];
    float* out = (float*)d_out;

    int C = in_sizes[2] / 4;            // conv_b is [4, C]
    int planes = in_sizes[0] / 3136;    // B*C planes of 56*56
    int pairs = planes / 2;             // plane p pairs with p+pairs (same channel: pairs % C == 0)

    pde_fused5<<<pairs, 448, 0, stream>>>(x, cw, cb, bs, bb, bm, bv, out, C, pairs);
}

// Round 6
// 140.191 us; speedup vs baseline: 7.1715x; 1.1843x over previous
//
#include <hip/hip_runtime.h>

#define K_STEPS 10

typedef float f32x2 __attribute__((ext_vector_type(2)));
typedef float f32x4 __attribute__((ext_vector_type(4)));

__device__ __forceinline__ f32x2 fma2v(f32x2 a, f32x2 b, f32x2 c) {
    return __builtin_elementwise_fma(a, b, c);
}

__global__ __launch_bounds__(448)
void pde_fused6(const float* __restrict__ x,
                const float* __restrict__ conv_w,
                const float* __restrict__ conv_b,
                const float* __restrict__ bn_s,
                const float* __restrict__ bn_b,
                const float* __restrict__ bn_m,
                const float* __restrict__ bn_v,
                float* __restrict__ out,
                int C, int quads)
{
    // 6500 f32x4 cells = 104000 B: xs [58][58] padded | hA [56][56]; hB aliases xs.
    // f32x4 lane p = plane (bid + p*quads); all share channel since quads % C == 0.
    extern __shared__ f32x4 smem[];
    const float DTc = 0.2f, EPSc = 1e-5f;
    const int tid = threadIdx.x;
    const int bid = blockIdx.x;
    const int ch  = bid % C;

    const size_t base0 = (size_t)bid * 3136;
    const size_t base1 = (size_t)(bid + quads) * 3136;
    const size_t base2 = (size_t)(bid + 2 * quads) * 3136;
    const size_t base3 = (size_t)(bid + 3 * quads) * 3136;

    f32x4* xs = smem;            // [58][58] zero-padded x tile
    f32x4* hA = smem + 3364;     // [56][56]
    f32x4* hB = smem;            // aliases xs (dead after setup)

    // ---- zero padded staging tile ----
    for (int i = tid; i < 3364; i += 448) {
        f32x4 z = {0.0f, 0.0f, 0.0f, 0.0f};
        xs[i] = z;
    }
    __syncthreads();

    // ---- coalesced global loads, all four planes ----
    float xv0[7], xv1[7], xv2[7], xv3[7];
    #pragma unroll
    for (int k = 0; k < 7; ++k) xv0[k] = x[base0 + tid + k * 448];
    #pragma unroll
    for (int k = 0; k < 7; ++k) xv1[k] = x[base1 + tid + k * 448];
    #pragma unroll
    for (int k = 0; k < 7; ++k) xv2[k] = x[base2 + tid + k * 448];
    #pragma unroll
    for (int k = 0; k < 7; ++k) xv3[k] = x[base3 + tid + k * 448];

    // ---- per-channel uniforms (block-uniform -> scalar loads) ----
    float wj[4][9], cbj[4];
    #pragma unroll
    for (int j = 0; j < 4; ++j) {
        #pragma unroll
        for (int tt = 0; tt < 9; ++tt) wj[j][tt] = conv_w[(j * C + ch) * 9 + tt];
        cbj[j] = conv_b[j * C + ch];
    }
    float g[5], be[5];
    #pragma unroll
    for (int j = 0; j < 5; ++j) {
        float inv = bn_s[j * C + ch] * rsqrtf(bn_v[j * C + ch] + EPSc);
        g[j]  = inv;
        be[j] = bn_b[j * C + ch] - bn_m[j * C + ch] * inv;
    }

    #pragma unroll
    for (int k = 0; k < 7; ++k) {
        int idx = tid + k * 448;
        int rr = idx / 56, cc = idx - rr * 56;
        f32x4 t;
        t.x = xv0[k]; t.y = xv1[k]; t.z = xv2[k]; t.w = xv3[k];
        xs[(rr + 1) * 58 + (cc + 1)] = t;
    }
    __syncthreads();

    // ---- this thread's 1x7 chunk: row r, cols c0..c0+6 ----
    const int r  = tid >> 3;
    const int c0 = (tid & 7) * 7;

    // coefficient state, two f32x2 halves per quantity (planes 01 / 23)
    f32x2 h01[7], F01[7], A01[7], Xp01[7], Xm01[7], Yp01[7], Ym01[7];
    f32x2 h23[7], F23[7], A23[7], Xp23[7], Xm23[7], Yp23[7], Ym23[7];
    const f32x2* xs2 = (const f32x2*)xs;   // cell c half h at xs2[c*2 + h]

    // conv + BN + activations, one half-pair at a time (caps register peak)
#define SETUP(HS, H, F, A, XP, XM, YP, YM) do {                               \
    f32x2 win[3][9];                                                          \
    _Pragma("unroll")                                                         \
    for (int dr = 0; dr < 3; ++dr)                                            \
        _Pragma("unroll")                                                     \
        for (int dc = 0; dc < 9; ++dc)                                        \
            win[dr][dc] = xs2[((r + dr) * 58 + c0 + dc) * 2 + (HS)];          \
    _Pragma("unroll")                                                         \
    for (int i = 0; i < 7; ++i) {                                             \
        f32x2 a0 = {cbj[0], cbj[0]};                                          \
        f32x2 a1 = {cbj[1], cbj[1]};                                          \
        f32x2 a2 = {cbj[2], cbj[2]};                                          \
        f32x2 a3 = {cbj[3], cbj[3]};                                          \
        _Pragma("unroll")                                                     \
        for (int dr = 0; dr < 3; ++dr)                                        \
            _Pragma("unroll")                                                 \
            for (int dc = 0; dc < 3; ++dc) {                                  \
                f32x2 xw = win[dr][i + dc];                                   \
                float w;                                                      \
                w = wj[0][dr * 3 + dc]; a0 = fma2v(xw, (f32x2){w, w}, a0);    \
                w = wj[1][dr * 3 + dc]; a1 = fma2v(xw, (f32x2){w, w}, a1);    \
                w = wj[2][dr * 3 + dc]; a2 = fma2v(xw, (f32x2){w, w}, a2);    \
                w = wj[3][dr * 3 + dc]; a3 = fma2v(xw, (f32x2){w, w}, a3);    \
            }                                                                 \
        float uux = fmaxf(fmaf(a0.x, g[0], be[0]), 0.0f);                     \
        float uuy = fmaxf(fmaf(a0.y, g[0], be[0]), 0.0f);                     \
        float vvx = fmaxf(fmaf(a1.x, g[1], be[1]), 0.0f);                     \
        float vvy = fmaxf(fmaf(a1.y, g[1], be[1]), 0.0f);                     \
        float z2x = fmaf(a2.x, g[2], be[2]), z2y = fmaf(a2.y, g[2], be[2]);   \
        float z3x = fmaf(a3.x, g[3], be[3]), z3y = fmaf(a3.y, g[3], be[3]);   \
        float Dxx = 1.0f / (1.0f + __expf(-z2x));                             \
        float Dxy = 1.0f / (1.0f + __expf(-z2y));                             \
        float Dyx = 1.0f / (1.0f + __expf(-z3x));                             \
        float Dyy = 1.0f / (1.0f + __expf(-z3y));                             \
        float Ax = DTc * Dxx, Ay = DTc * Dxy;                                 \
        float Bx = DTc * Dyx, By = DTc * Dyy;                                 \
        float Ux = 0.5f * DTc * uux, Uy = 0.5f * DTc * uuy;                   \
        float Vx = 0.5f * DTc * vvx, Vy = 0.5f * DTc * vvy;                   \
        f32x2 hv = win[1][i + 1];                                             \
        (H)[i]  = hv;                                                         \
        (F)[i]  = (f32x2){DTc * hv.x, DTc * hv.y};                            \
        (A)[i]  = (f32x2){1.0f - 2.0f * Ax - 2.0f * Bx,                       \
                          1.0f - 2.0f * Ay - 2.0f * By};                      \
        (XP)[i] = (f32x2){Ax + Ux, Ay + Uy};                                  \
        (XM)[i] = (f32x2){Ax - Ux, Ay - Uy};                                  \
        (YP)[i] = (f32x2){Bx + Vx, By + Vy};                                  \
        (YM)[i] = (f32x2){Bx - Vx, By - Vy};                                  \
    }                                                                         \
} while (0)

    SETUP(0, h01, F01, A01, Xp01, Xm01, Yp01, Ym01);
    SETUP(1, h23, F23, A23, Xp23, Xm23, Yp23, Ym23);
#undef SETUP

    // initial h into buffer A
    const int o_me = r * 56 + c0;
    #pragma unroll
    for (int i = 0; i < 7; ++i)
        hA[o_me + i] = __builtin_shufflevector(h01[i], h23[i], 0, 1, 2, 3);
    __syncthreads();

    // periodic-wrap neighbor offsets (jnp.roll semantics)
    const int rm = (r == 0)  ? 55 : r - 1;
    const int rp = (r == 55) ? 0  : r + 1;
    const int o_up = rm * 56 + c0;
    const int o_dn = rp * 56 + c0;
    const int o_l  = r * 56 + ((c0 == 0)  ? 55 : c0 - 1);
    const int o_r  = r * 56 + ((c0 == 49) ? 0  : c0 + 7);

    f32x4 *cur = hA, *nxt = hB;
    #pragma unroll
    for (int s = 0; s < K_STEPS; ++s) {
        f32x4 up4[7], dn4[7];
        #pragma unroll
        for (int i = 0; i < 7; ++i) up4[i] = cur[o_up + i];
        #pragma unroll
        for (int i = 0; i < 7; ++i) dn4[i] = cur[o_dn + i];
        f32x4 lf4 = cur[o_l];
        f32x4 rg4 = cur[o_r];

        f32x2 nh01[7], nh23[7];
        #pragma unroll
        for (int i = 0; i < 7; ++i) {
            f32x2 hl = (i == 0) ? lf4.xy : h01[i - 1];
            f32x2 hr = (i == 6) ? rg4.xy : h01[i + 1];
            f32x2 tv = fma2v(A01[i], h01[i], F01[i]);
            tv = fma2v(Xm01[i], up4[i].xy, tv);
            tv = fma2v(Xp01[i], dn4[i].xy, tv);
            tv = fma2v(Ym01[i], hl, tv);
            tv = fma2v(Yp01[i], hr, tv);
            nh01[i] = tv;
        }
        #pragma unroll
        for (int i = 0; i < 7; ++i) {
            f32x2 hl = (i == 0) ? lf4.zw : h23[i - 1];
            f32x2 hr = (i == 6) ? rg4.zw : h23[i + 1];
            f32x2 tv = fma2v(A23[i], h23[i], F23[i]);
            tv = fma2v(Xm23[i], up4[i].zw, tv);
            tv = fma2v(Xp23[i], dn4[i].zw, tv);
            tv = fma2v(Ym23[i], hl, tv);
            tv = fma2v(Yp23[i], hr, tv);
            nh23[i] = tv;
        }
        #pragma unroll
        for (int i = 0; i < 7; ++i)
            nxt[o_me + i] = __builtin_shufflevector(nh01[i], nh23[i], 0, 1, 2, 3);
        #pragma unroll
        for (int i = 0; i < 7; ++i) { h01[i] = nh01[i]; h23[i] = nh23[i]; }
        __syncthreads();
        f32x4* t2 = cur; cur = nxt; nxt = t2;
    }

    // ---- final bn4 + relu, coalesced stores via LDS re-read ----
    #pragma unroll
    for (int k = 0; k < 7; ++k) {
        int idx = tid + k * 448;
        f32x4 v = cur[idx];
        out[base0 + idx] = fmaxf(fmaf(v.x, g[4], be[4]), 0.0f);
        out[base1 + idx] = fmaxf(fmaf(v.y, g[4], be[4]), 0.0f);
        out[base2 + idx] = fmaxf(fmaf(v.z, g[4], be[4]), 0.0f);
        out[base3 + idx] = fmaxf(fmaf(v.w, g[4], be[4]), 0.0f);
    }
}

extern "C" void kernel_launch(void* const* d_in, const int* in_sizes, int n_in,
                              void* d_out, int out_size, void* d_ws, size_t ws_size,
                              hipStream_t stream) {
    const float* x  = (const float*)d_in[0];
    const float* cw = (const float*)d_in[1];
    const float* cb = (const float*)d_in[2];
    const float* bs = (const float*)d_in[3];
    const float* bb = (const float*)d_in[4];
    const float* bm = (const float*)d_in[5];
    const float* bv = (const float*)d_in[6];
    float* out = (float*)d_out;

    int C = in_sizes[2] / 4;            // conv_b is [4, C]
    int planes = in_sizes[0] / 3136;    // B*C planes of 56*56
    int quads = planes / 4;             // plane p pairs with p+q, p+2q, p+3q (same channel: quads % C == 0)

    const size_t smem_bytes = 6500 * sizeof(f32x4);  // 104000 B dynamic LDS
    // host-side attribute set: not a stream op, graph-capture safe, idempotent
    hipFuncSetAttribute((const void*)pde_fused6,
                        hipFuncAttributeMaxDynamicSharedMemorySize,
                        (int)smem_bytes);

    pde_fused6<<<quads, 448, smem_bytes, stream>>>(x, cw, cb, bs, bb, bm, bv, out, C, quads);
}

// Round 7
// 138.945 us; speedup vs baseline: 7.2357x; 1.0090x over previous
//
#include <hip/hip_runtime.h>

#define K_STEPS 10

__device__ __forceinline__ float2 fma2(float2 a, float2 b, float2 c) {
    return make_float2(fmaf(a.x, b.x, c.x), fmaf(a.y, b.y, c.y));
}

__global__ __launch_bounds__(448, 4)
void pde_fused7(const float* __restrict__ x,
                const float* __restrict__ conv_w,
                const float* __restrict__ conv_b,
                const float* __restrict__ bn_s,
                const float* __restrict__ bn_b,
                const float* __restrict__ bn_m,
                const float* __restrict__ bn_v,
                float* __restrict__ out,
                int C, int pairs)
{
    const float DTc = 0.2f, EPSc = 1e-5f;
    // float2 = {plane bid, plane bid+pairs}; same channel since pairs % C == 0
    __shared__ float2 smem[6500];
    const int tid = threadIdx.x;
    const int bid = blockIdx.x;
    const int ch  = bid % C;
    const size_t base0 = (size_t)bid * 3136;
    const size_t base1 = (size_t)(bid + pairs) * 3136;

    float2* xs = smem;          // [58][58] zero-padded x tile (both planes)
    float2* hA = smem + 3364;   // [56][56]
    float2* hB = smem;          // aliases xs (dead after setup)

    // ---- zero padded staging tile ----
    for (int i = tid; i < 3364; i += 448) xs[i] = make_float2(0.0f, 0.0f);
    __syncthreads();

    // ---- coalesced global loads, both planes ----
    float xv0[7], xv1[7];
    #pragma unroll
    for (int k = 0; k < 7; ++k) xv0[k] = x[base0 + tid + k * 448];
    #pragma unroll
    for (int k = 0; k < 7; ++k) xv1[k] = x[base1 + tid + k * 448];

    // ---- per-channel uniforms (block-uniform -> SGPRs) ----
    float wj[4][9], cbj[4];
    #pragma unroll
    for (int j = 0; j < 4; ++j) {
        #pragma unroll
        for (int tt = 0; tt < 9; ++tt) wj[j][tt] = conv_w[(j * C + ch) * 9 + tt];
        cbj[j] = conv_b[j * C + ch];
    }
    float g[5], be[5];
    #pragma unroll
    for (int j = 0; j < 5; ++j) {
        float inv = bn_s[j * C + ch] * rsqrtf(bn_v[j * C + ch] + EPSc);
        g[j]  = inv;
        be[j] = bn_b[j * C + ch] - bn_m[j * C + ch] * inv;
    }

    #pragma unroll
    for (int k = 0; k < 7; ++k) {
        int idx = tid + k * 448;
        int rr = idx / 56, cc = idx - rr * 56;
        xs[(rr + 1) * 58 + (cc + 1)] = make_float2(xv0[k], xv1[k]);
    }
    __syncthreads();

    // ---- this thread's 1x7 chunk: row r, cols c0..c0+6 (both planes) ----
    const int r  = tid >> 3;
    const int c0 = (tid & 7) * 7;

    // coefficient state: h' = A*h + Xm*up + Xp*dn + Ym*l + Yp*r + F
    float2 h[7], F[7], A[7], Xp[7], Xm[7], Yp[7], Ym[7];

    // per-cell 3x3 windows (9 transient f32x2) to cap setup register liveness
    #pragma unroll
    for (int i = 0; i < 7; ++i) {
        float2 a0 = make_float2(cbj[0], cbj[0]);
        float2 a1 = make_float2(cbj[1], cbj[1]);
        float2 a2 = make_float2(cbj[2], cbj[2]);
        float2 a3 = make_float2(cbj[3], cbj[3]);
        float2 hv;
        #pragma unroll
        for (int dr = 0; dr < 3; ++dr)
            #pragma unroll
            for (int dc = 0; dc < 3; ++dc) {
                float2 xw = xs[(r + dr) * 58 + (c0 + i + dc)];
                if (dr == 1 && dc == 1) hv = xw;
                float w0 = wj[0][dr * 3 + dc], w1 = wj[1][dr * 3 + dc];
                float w2 = wj[2][dr * 3 + dc], w3 = wj[3][dr * 3 + dc];
                a0 = fma2(xw, make_float2(w0, w0), a0);
                a1 = fma2(xw, make_float2(w1, w1), a1);
                a2 = fma2(xw, make_float2(w2, w2), a2);
                a3 = fma2(xw, make_float2(w3, w3), a3);
            }
        float uux = fmaxf(fmaf(a0.x, g[0], be[0]), 0.0f);
        float uuy = fmaxf(fmaf(a0.y, g[0], be[0]), 0.0f);
        float vvx = fmaxf(fmaf(a1.x, g[1], be[1]), 0.0f);
        float vvy = fmaxf(fmaf(a1.y, g[1], be[1]), 0.0f);
        float z2x = fmaf(a2.x, g[2], be[2]), z2y = fmaf(a2.y, g[2], be[2]);
        float z3x = fmaf(a3.x, g[3], be[3]), z3y = fmaf(a3.y, g[3], be[3]);
        float Dxx = 1.0f / (1.0f + __expf(-z2x));
        float Dxy = 1.0f / (1.0f + __expf(-z2y));
        float Dyx = 1.0f / (1.0f + __expf(-z3x));
        float Dyy = 1.0f / (1.0f + __expf(-z3y));
        float Ax = DTc * Dxx, Ay = DTc * Dxy;
        float Bx = DTc * Dyx, By = DTc * Dyy;
        float Ux = 0.5f * DTc * uux, Uy = 0.5f * DTc * uuy;
        float Vx = 0.5f * DTc * vvx, Vy = 0.5f * DTc * vvy;
        h[i]  = hv;
        F[i]  = make_float2(DTc * hv.x, DTc * hv.y);
        A[i]  = make_float2(1.0f - 2.0f * Ax - 2.0f * Bx,
                            1.0f - 2.0f * Ay - 2.0f * By);
        Xp[i] = make_float2(Ax + Ux, Ay + Uy);
        Xm[i] = make_float2(Ax - Ux, Ay - Uy);
        Yp[i] = make_float2(Bx + Vx, By + Vy);
        Ym[i] = make_float2(Bx - Vx, By - Vy);
    }

    // initial h into buffer A
    const int o_me = r * 56 + c0;
    #pragma unroll
    for (int i = 0; i < 7; ++i) hA[o_me + i] = h[i];
    __syncthreads();

    // periodic-wrap neighbor offsets (jnp.roll semantics)
    const int rm = (r == 0)  ? 55 : r - 1;
    const int rp = (r == 55) ? 0  : r + 1;
    const int o_up = rm * 56 + c0;
    const int o_dn = rp * 56 + c0;
    const int o_l  = r * 56 + ((c0 == 0)  ? 55 : c0 - 1);
    const int o_r  = r * 56 + ((c0 == 49) ? 0  : c0 + 7);

    float2 *cur = hA, *nxt = hB;
    #pragma unroll
    for (int s = 0; s < K_STEPS; ++s) {
        float2 lf = cur[o_l];
        float2 rg = cur[o_r];
        float2 nh[7];
        // inline per-cell up/dn reads (no 28-reg staging arrays); TLP from
        // 2 co-resident blocks hides the LDS latency
        #pragma unroll
        for (int i = 0; i < 7; ++i) {
            float2 ui = cur[o_up + i];
            float2 di = cur[o_dn + i];
            float2 hl = (i == 0) ? lf : h[i - 1];
            float2 hr = (i == 6) ? rg : h[i + 1];
            float2 tv = fma2(A[i], h[i], F[i]);
            tv = fma2(Xm[i], ui, tv);
            tv = fma2(Xp[i], di, tv);
            tv = fma2(Ym[i], hl, tv);
            tv = fma2(Yp[i], hr, tv);
            nh[i] = tv;
        }
        #pragma unroll
        for (int i = 0; i < 7; ++i) nxt[o_me + i] = nh[i];
        #pragma unroll
        for (int i = 0; i < 7; ++i) h[i] = nh[i];
        __syncthreads();
        float2* t2 = cur; cur = nxt; nxt = t2;
    }

    // ---- final bn4 + relu, coalesced stores via LDS re-read ----
    #pragma unroll
    for (int k = 0; k < 7; ++k) {
        int idx = tid + k * 448;
        float2 v = cur[idx];
        out[base0 + idx] = fmaxf(fmaf(v.x, g[4], be[4]), 0.0f);
        out[base1 + idx] = fmaxf(fmaf(v.y, g[4], be[4]), 0.0f);
    }
}

extern "C" void kernel_launch(void* const* d_in, const int* in_sizes, int n_in,
                              void* d_out, int out_size, void* d_ws, size_t ws_size,
                              hipStream_t stream) {
    const float* x  = (const float*)d_in[0];
    const float* cw = (const float*)d_in[1];
    const float* cb = (const float*)d_in[2];
    const float* bs = (const float*)d_in[3];
    const float* bb = (const float*)d_in[4];
    const float* bm = (const float*)d_in[5];
    const float* bv = (const float*)d_in[6];
    float* out = (float*)d_out;

    int C = in_sizes[2] / 4;            // conv_b is [4, C]
    int planes = in_sizes[0] / 3136;    // B*C planes of 56*56
    int pairs = planes / 2;             // plane p pairs with p+pairs (same channel: pairs % C == 0)

    pde_fused7<<<pairs, 448, 0, stream>>>(x, cw, cb, bs, bb, bm, bv, out, C, pairs);
}